// Round 1
// baseline (219.612 us; speedup 1.0000x reference)
//
#include <hip/hip_runtime.h>
#include <stdint.h>

// ClusterHead: P = softmax_k( x . c_k - 0.5*||c_k||^2 )  (||x||^2 cancels)
// Split-bf16 GEMM: x.c = x_hi.c_hi + x_hi.c_lo + x_lo.c_hi  as one bf16 GEMM
// with K' = 3*512 = 1536 (regions: A = [hi, hi, lo], B = [hi, lo, hi]).

namespace {
constexpr int N_ROWS  = 32768;
constexpr int K_CL    = 1024;   // clusters (GEMM N)
constexpr int D_DIM   = 512;
constexpr int BK      = 32;
constexpr int NSTEPS  = 48;     // 3*D / BK
constexpr int BM      = 64;
constexpr int STRIDE  = 40;     // bf16 elems per k-slice row (32 real + 8 pad) = 80B (odd*16B)
constexpr int THREADS = 512;
constexpr int WAVES   = 8;
constexpr size_t BSTEP_BYTES = (size_t)K_CL * STRIDE * 2;  // 81920 B per k-step image
}

typedef __bf16 bf16_t;
typedef __bf16 bf16x8 __attribute__((ext_vector_type(8)));
typedef __bf16 bf16x4 __attribute__((ext_vector_type(4)));
typedef float  f32x4  __attribute__((ext_vector_type(4)));

__device__ inline void async_copy16(const void* g, void* l) {
  __builtin_amdgcn_global_load_lds(
      (const __attribute__((address_space(1))) uint32_t*)g,
      (__attribute__((address_space(3))) uint32_t*)l, 16, 0, 0);
}

// ---- prep: build padded bf16 B' image (LDS-image layout) + bias = -0.5*||c||^2
__global__ __launch_bounds__(64) void prep_kernel(const float* __restrict__ centers,
                                                  bf16_t* __restrict__ bpack,
                                                  float* __restrict__ bias) {
  const int col  = blockIdx.x;      // 0..1023
  const int lane = threadIdx.x;     // 0..63
  const float* crow = centers + (size_t)col * D_DIM;
  float ssq = 0.f;
  for (int d = lane; d < D_DIM; d += 64) {
    float v = crow[d];
    ssq += v * v;
    bf16_t hi = (bf16_t)v;
    bf16_t lo = (bf16_t)(v - (float)hi);
    int t = d >> 5, e = d & 31;
    // region 0: c_hi (steps 0..15), region 1: c_lo (16..31), region 2: c_hi (32..47)
    bpack[((size_t)(t)      * K_CL + col) * STRIDE + e] = hi;
    bpack[((size_t)(16 + t) * K_CL + col) * STRIDE + e] = lo;
    bpack[((size_t)(32 + t) * K_CL + col) * STRIDE + e] = hi;
  }
  for (int off = 32; off; off >>= 1) ssq += __shfl_down(ssq, off, 64);
  if (lane == 0) bias[col] = -0.5f * ssq;
}

// ---- main fused kernel: 64 rows x 1024 cols per block, fused softmax
__global__ __launch_bounds__(THREADS) void cluster_kernel(
    const float* __restrict__ x, const bf16_t* __restrict__ bpack,
    const float* __restrict__ bias, float* __restrict__ out) {
  __shared__ bf16_t Alds[BM * STRIDE];        //  5 KB
  __shared__ bf16_t Blds[K_CL * STRIDE];      // 80 KB
  __shared__ float  bias_lds[K_CL];           //  4 KB
  __shared__ float  red[WAVES * BM];          //  2 KB
  __shared__ float  fin[BM];

  const int tid  = threadIdx.x;
  const int wid  = tid >> 6;
  const int lane = tid & 63;
  const int g    = lane >> 4;                 // k-chunk group 0..3
  const int l15  = lane & 15;
  const int brow = blockIdx.x * BM;

  for (int i = tid; i < K_CL; i += THREADS) bias_lds[i] = bias[i];

  f32x4 acc[4][8];
  #pragma unroll
  for (int rb = 0; rb < 4; ++rb)
    #pragma unroll
    for (int cb = 0; cb < 8; ++cb) acc[rb][cb] = (f32x4){0.f, 0.f, 0.f, 0.f};

  // A staging: thread loads 4 consecutive fp32 of one row
  const int arow  = tid >> 3;
  const int acol4 = (tid & 7) * 4;
  const float* xptr = x + (size_t)(brow + arow) * D_DIM + acol4;

  const char* bsrc = (const char*)bpack;
  char* ldst = (char*)Blds + wid * 10240;

  for (int t = 0; t < NSTEPS; ++t) {
    __syncthreads();   // previous step's LDS reads complete

    // --- stage A (convert fp32 -> bf16 hi or lo per region)
    {
      const int kk = t * BK;
      const int xc = kk & (D_DIM - 1);
      float4 v = *(const float4*)(xptr + xc);
      bf16x4 w;
      if (kk < 2 * D_DIM) {  // regions 0,1 -> x_hi
        w = (bf16x4){(bf16_t)v.x, (bf16_t)v.y, (bf16_t)v.z, (bf16_t)v.w};
      } else {               // region 2 -> x_lo
        bf16_t h0 = (bf16_t)v.x, h1 = (bf16_t)v.y, h2 = (bf16_t)v.z, h3 = (bf16_t)v.w;
        w = (bf16x4){(bf16_t)(v.x - (float)h0), (bf16_t)(v.y - (float)h1),
                     (bf16_t)(v.z - (float)h2), (bf16_t)(v.w - (float)h3)};
      }
      *(bf16x4*)&Alds[arow * STRIDE + acol4] = w;
    }

    // --- stage B: async DMA of pre-padded 80KB image (identity byte layout)
    {
      const char* gsrc = bsrc + (size_t)t * BSTEP_BYTES + wid * 10240 + lane * 16;
      #pragma unroll
      for (int i = 0; i < 10; ++i)
        async_copy16(gsrc + i * 1024, ldst + i * 1024);
    }

    __syncthreads();   // drains vmcnt + lgkmcnt

    // --- compute: wave owns 64 rows x 128 cols
    bf16x8 afrag[4];
    #pragma unroll
    for (int rb = 0; rb < 4; ++rb)
      afrag[rb] = *(const bf16x8*)&Alds[(rb * 16 + l15) * STRIDE + g * 8];
    #pragma unroll
    for (int cb = 0; cb < 8; ++cb) {
      bf16x8 bfrag = *(const bf16x8*)&Blds[(wid * 128 + cb * 16 + l15) * STRIDE + g * 8];
      #pragma unroll
      for (int rb = 0; rb < 4; ++rb)
        acc[rb][cb] = __builtin_amdgcn_mfma_f32_16x16x32_bf16(afrag[rb], bfrag,
                                                              acc[rb][cb], 0, 0, 0);
    }
  }

  // ---- epilogue: fused softmax over the 1024 columns ----
  float bcol[8];
  #pragma unroll
  for (int cb = 0; cb < 8; ++cb) bcol[cb] = bias_lds[wid * 128 + cb * 16 + l15];

  // bias add + row max (rows: rb*16 + g*4 + j; cols vary over l15 and cb)
  float rmax[4][4];
  #pragma unroll
  for (int rb = 0; rb < 4; ++rb) {
    #pragma unroll
    for (int j = 0; j < 4; ++j) {
      float m = -3.0e38f;
      #pragma unroll
      for (int cb = 0; cb < 8; ++cb) {
        float v = acc[rb][cb][j] + bcol[cb];
        acc[rb][cb][j] = v;
        m = fmaxf(m, v);
      }
      m = fmaxf(m, __shfl_xor(m, 1, 64));
      m = fmaxf(m, __shfl_xor(m, 2, 64));
      m = fmaxf(m, __shfl_xor(m, 4, 64));
      m = fmaxf(m, __shfl_xor(m, 8, 64));
      rmax[rb][j] = m;
    }
  }
  if (l15 == 0) {
    #pragma unroll
    for (int rb = 0; rb < 4; ++rb)
      #pragma unroll
      for (int j = 0; j < 4; ++j)
        red[wid * BM + rb * 16 + g * 4 + j] = rmax[rb][j];
  }
  __syncthreads();
  if (tid < BM) {
    float m = red[tid];
    #pragma unroll
    for (int w = 1; w < WAVES; ++w) m = fmaxf(m, red[w * BM + tid]);
    fin[tid] = m;
  }
  __syncthreads();

  // exp + row sum
  #pragma unroll
  for (int rb = 0; rb < 4; ++rb) {
    #pragma unroll
    for (int j = 0; j < 4; ++j) {
      float m = fin[rb * 16 + g * 4 + j];
      float s = 0.f;
      #pragma unroll
      for (int cb = 0; cb < 8; ++cb) {
        float e = __expf(acc[rb][cb][j] - m);
        acc[rb][cb][j] = e;
        s += e;
      }
      s += __shfl_xor(s, 1, 64);
      s += __shfl_xor(s, 2, 64);
      s += __shfl_xor(s, 4, 64);
      s += __shfl_xor(s, 8, 64);
      rmax[rb][j] = s;   // reuse as partial sum
    }
  }
  __syncthreads();   // all fin(max) reads done before red overwrite below
  if (l15 == 0) {
    #pragma unroll
    for (int rb = 0; rb < 4; ++rb)
      #pragma unroll
      for (int j = 0; j < 4; ++j)
        red[wid * BM + rb * 16 + g * 4 + j] = rmax[rb][j];
  }
  __syncthreads();
  if (tid < BM) {
    float s = 0.f;
    #pragma unroll
    for (int w = 0; w < WAVES; ++w) s += red[w * BM + tid];
    fin[tid] = 1.0f / s;
  }
  __syncthreads();

  // normalize + store (16 consecutive floats per 16-lane group)
  float* outp = out + (size_t)brow * K_CL + wid * 128 + l15;
  #pragma unroll
  for (int rb = 0; rb < 4; ++rb) {
    #pragma unroll
    for (int j = 0; j < 4; ++j) {
      const int row = rb * 16 + g * 4 + j;
      const float rs = fin[row];
      #pragma unroll
      for (int cb = 0; cb < 8; ++cb)
        outp[(size_t)row * K_CL + cb * 16] = acc[rb][cb][j] * rs;
    }
  }
}

extern "C" void kernel_launch(void* const* d_in, const int* in_sizes, int n_in,
                              void* d_out, int out_size, void* d_ws, size_t ws_size,
                              hipStream_t stream) {
  const float* x       = (const float*)d_in[0];   // [32768, 512] fp32
  const float* centers = (const float*)d_in[1];   // [1024, 512] fp32
  float* out = (float*)d_out;                     // [32768, 1024] fp32

  bf16_t* bpack = (bf16_t*)d_ws;                                    // 48*81920 = 3.75 MB
  float*  bias  = (float*)((char*)d_ws + (size_t)NSTEPS * BSTEP_BYTES); // 4 KB

  prep_kernel<<<K_CL, 64, 0, stream>>>(centers, bpack, bias);
  cluster_kernel<<<N_ROWS / BM, THREADS, 0, stream>>>(x, bpack, bias, out);
}

// Round 3
// 119.044 us; speedup vs baseline: 1.8448x; 1.8448x over previous
//
#include <hip/hip_runtime.h>
#include <stdint.h>

// ClusterHead: P = softmax_k( x . c_k - 0.5*||c_k||^2 )   (||x||^2 cancels)
// Split-bf16: x.c = x_hi.c_hi + x_lo.c_hi + x_hi.c_lo.
// B-hi sub-images are used for BOTH the A-hi and A-lo MFMA passes, so only
// 2 B regions (hi, lo) are staged per k-slice (2MB total vs 3 regions).
// Pipeline: 3-deep B ring with counted vmcnt guards (never vmcnt(0) in loop).
// R3 fix: STAGE_B global source must be PER-LANE (+ lane*16) — global_load_lds
// appends lane*16 on the LDS dest only; R2 fed all lanes the same src address.

namespace {
constexpr int N_ROWS  = 32768;
constexpr int K_CL    = 1024;
constexpr int D_DIM   = 512;
constexpr int BM      = 64;
constexpr int THREADS = 512;
constexpr int WAVES   = 8;
constexpr int NSLICE  = 16;     // k-slices of 32
constexpr int NSUB    = 64;     // 4 sub-iters per slice: (hi,h0)(hi,h1)(lo,h0)(lo,h1)
}

typedef __bf16 bf16_t;
typedef __bf16 bf16x8 __attribute__((ext_vector_type(8)));
typedef __bf16 bf16x4 __attribute__((ext_vector_type(4)));
typedef float  f32x4  __attribute__((ext_vector_type(4)));

__device__ inline void async_copy16(const void* g, void* l) {
  __builtin_amdgcn_global_load_lds(
      (const __attribute__((address_space(1))) uint32_t*)g,
      (__attribute__((address_space(3))) uint32_t*)l, 16, 0, 0);
}

// ---- prep: bpack sub-images [s][g][col] 16B chunks (k-major, conflict-free)
// sub-image s = 4*t + j : j0/j1 = c_hi cols 0-511 / 512-1023, j2/j3 = c_lo halves.
__global__ __launch_bounds__(64) void prep_kernel(const float* __restrict__ centers,
                                                  bf16_t* __restrict__ bpack,
                                                  float* __restrict__ bias) {
  const int col = blockIdx.x, lane = threadIdx.x;
  const int t = lane >> 2, g = lane & 3;   // lane owns d in [lane*8, lane*8+8)
  const float* src = centers + (size_t)col * D_DIM + lane * 8;
  bf16x8 hi, lo;
  float ssq = 0.f;
  #pragma unroll
  for (int i = 0; i < 8; ++i) {
    float v = src[i];
    ssq += v * v;
    bf16_t h = (bf16_t)v;
    hi[i] = h;
    lo[i] = (bf16_t)(v - (float)h);
  }
  const int jh = col >> 9, c = col & 511;
  *(bf16x8*)(bpack + ((size_t)(4 * t + jh)     * 2048 + g * 512 + c) * 8) = hi;
  *(bf16x8*)(bpack + ((size_t)(4 * t + 2 + jh) * 2048 + g * 512 + c) * 8) = lo;
  for (int off = 32; off; off >>= 1) ssq += __shfl_down(ssq, off, 64);
  if (lane == 0) bias[col] = -0.5f * ssq;
}

// ---- main fused kernel: 64 rows x 1024 cols per block, pipelined K loop
__global__ __launch_bounds__(THREADS, 2) void cluster_kernel(
    const float* __restrict__ x, const bf16_t* __restrict__ bpack,
    const float* __restrict__ bias, float* __restrict__ out) {
  __shared__ bf16_t Bbuf[3][16384];     // 3 x 32KB ring
  __shared__ bf16_t Abuf[2][2][2048];   // [slice&1][hi/lo][ [g][row] 16B chunks ] 16KB
  __shared__ float  Xstage[2][2048];    // fp32 x slice ping-pong, 2 x 8KB
  __shared__ float  bias_lds[K_CL];     // 4KB
  __shared__ float  red[WAVES * BM];    // 2KB (epilogue)
  __shared__ float  fin[BM];
  __shared__ char   Bscratch[1024];     // dummy-DMA sink (tail)

  const int tid  = threadIdx.x;
  const int wid  = tid >> 6;
  const int lane = tid & 63;
  const int g    = lane >> 4;
  const int l15  = lane & 15;
  const int brow = blockIdx.x * BM;
  const int arow = tid >> 3, q = tid & 7, ag = q >> 1, ah = q & 1;

  f32x4 acc[4][8];
  #pragma unroll
  for (int rb = 0; rb < 4; ++rb)
    #pragma unroll
    for (int cc = 0; cc < 8; ++cc) acc[rb][cc] = (f32x4){0.f, 0.f, 0.f, 0.f};

  // ---- staging helpers (LDS dest wave-uniform; global src PER-LANE) ----
#define STAGE_B(SIDX, DSTBASE)                                                 \
  {                                                                            \
    const char* gs_ = (const char*)bpack + (size_t)(SIDX) * 32768 +            \
                      wid * 4096 + lane * 16;                                  \
    char* ld_ = (char*)(DSTBASE) + wid * 4096;                                 \
    _Pragma("unroll")                                                          \
    for (int i_ = 0; i_ < 4; ++i_)                                             \
      async_copy16(gs_ + i_ * 1024, ld_ + i_ * 1024);                          \
  }
#define STAGE_X(TSRC, TB)                                                      \
  {                                                                            \
    const float* gs_ = x + (size_t)(brow + arow) * D_DIM + (TSRC) * 32 + q * 4;\
    char* ld_ = (char*)&Xstage[(TB)][0] + wid * 1024;                          \
    async_copy16(gs_, ld_);                                                    \
  }

  // ---- prologue: bias, X(0), B(0), B(1) ----
  float2 bv = *(const float2*)(bias + tid * 2);        // issued first -> exact wait
  STAGE_X(0, 0);
  STAGE_B(0, &Bbuf[0][0]);
  STAGE_B(1, &Bbuf[1][0]);
  *(float2*)&bias_lds[tid * 2] = bv;
  asm volatile("s_waitcnt vmcnt(8)" ::: "memory");     // X(0) arrived (8 B-loads in flight)
  {
    float4 xv = *(const float4*)&Xstage[0][tid * 4];
    bf16x4 h4, l4;
    float vv[4] = {xv.x, xv.y, xv.z, xv.w};
    #pragma unroll
    for (int i = 0; i < 4; ++i) {
      bf16_t h = (bf16_t)vv[i];
      h4[i] = h;
      l4[i] = (bf16_t)(vv[i] - (float)h);
    }
    *(bf16x4*)&Abuf[0][0][((ag * 64 + arow) * 8 + ah * 4)] = h4;
    *(bf16x4*)&Abuf[0][1][((ag * 64 + arow) * 8 + ah * 4)] = l4;
  }
  asm volatile("s_waitcnt vmcnt(4) lgkmcnt(0)" ::: "memory");  // B(0) done, B(1) in flight
  __builtin_amdgcn_s_barrier();
  __builtin_amdgcn_sched_barrier(0);

  bf16x8 ahi[4], alo[4];

  // ---- main loop: 16 slices x 4 sub-iters ----
  for (int t = 0; t < NSLICE; ++t) {
    const int tb = t & 1;
    const int s0 = 4 * t;

    // ---------- sub-iter J (compute on Bbuf[(s0+J)%3]) ----------
#define COMPUTE(J, WITH_LO)                                                    \
    {                                                                          \
      const bf16_t* bb = &Bbuf[(s0 + (J)) % 3][0];                             \
      _Pragma("unroll")                                                        \
      for (int cb = 0; cb < 4; ++cb) {                                         \
        bf16x8 bfrag = *(const bf16x8*)&bb[((g * 512 + wid * 64 + cb * 16 + l15)) * 8]; \
        _Pragma("unroll")                                                      \
        for (int rb = 0; rb < 4; ++rb)                                         \
          acc[rb][((J)&1) * 4 + cb] = __builtin_amdgcn_mfma_f32_16x16x32_bf16( \
              ahi[rb], bfrag, acc[rb][((J)&1) * 4 + cb], 0, 0, 0);             \
        if (WITH_LO) {                                                         \
          _Pragma("unroll")                                                    \
          for (int rb = 0; rb < 4; ++rb)                                       \
            acc[rb][((J)&1) * 4 + cb] = __builtin_amdgcn_mfma_f32_16x16x32_bf16( \
                alo[rb], bfrag, acc[rb][((J)&1) * 4 + cb], 0, 0, 0);           \
        }                                                                      \
      }                                                                        \
    }
#define STAGE_NEXT(J)                                                          \
    {                                                                          \
      const int s2 = s0 + (J) + 2;                                             \
      if (s2 < NSUB) {                                                         \
        STAGE_B(s2, &Bbuf[s2 % 3][0]);                                         \
      } else {  /* dummy: keep vmcnt counts uniform */                         \
        const char* gs_ = (const char*)bpack + (size_t)(s2 & 63) * 32768 +     \
                          lane * 16;                                           \
        _Pragma("unroll")                                                      \
        for (int i_ = 0; i_ < 4; ++i_)                                         \
          async_copy16(gs_ + i_ * 1024, (char*)Bscratch);                      \
      }                                                                        \
    }
#define FENCE(VMSTR)                                                           \
    asm volatile(VMSTR ::: "memory");                                          \
    __builtin_amdgcn_s_barrier();                                              \
    __builtin_amdgcn_sched_barrier(0);

    // ---- J = 0: B-hi half0, A hi+lo; load afrags; issue B(s+2), X(t+1) ----
    #pragma unroll
    for (int rb = 0; rb < 4; ++rb) {
      ahi[rb] = *(const bf16x8*)&Abuf[tb][0][(g * 64 + rb * 16 + l15) * 8];
      alo[rb] = *(const bf16x8*)&Abuf[tb][1][(g * 64 + rb * 16 + l15) * 8];
    }
    COMPUTE(0, 1)
    STAGE_NEXT(0)
    STAGE_X((t + 1) & 15, (t + 1) & 1)
    FENCE("s_waitcnt vmcnt(5) lgkmcnt(0)")

    // ---- J = 1: B-hi half1, A hi+lo ----
    COMPUTE(1, 1)
    STAGE_NEXT(1)
    FENCE("s_waitcnt vmcnt(5) lgkmcnt(0)")

    // ---- J = 2: B-lo half0, A hi only; convert X(t+1) -> Abuf[(t+1)&1] ----
    asm volatile("s_waitcnt vmcnt(4)" ::: "memory");   // X(t+1) arrived
    {
      float4 xv = *(const float4*)&Xstage[(t + 1) & 1][tid * 4];
      bf16x4 h4, l4;
      float vv[4] = {xv.x, xv.y, xv.z, xv.w};
      #pragma unroll
      for (int i = 0; i < 4; ++i) {
        bf16_t h = (bf16_t)vv[i];
        h4[i] = h;
        l4[i] = (bf16_t)(vv[i] - (float)h);
      }
      *(bf16x4*)&Abuf[(t + 1) & 1][0][((ag * 64 + arow) * 8 + ah * 4)] = h4;
      *(bf16x4*)&Abuf[(t + 1) & 1][1][((ag * 64 + arow) * 8 + ah * 4)] = l4;
    }
    COMPUTE(2, 0)
    STAGE_NEXT(2)
    FENCE("s_waitcnt vmcnt(4) lgkmcnt(0)")

    // ---- J = 3: B-lo half1, A hi only ----
    COMPUTE(3, 0)
    STAGE_NEXT(3)
    FENCE("s_waitcnt vmcnt(4) lgkmcnt(0)")
  }

  __syncthreads();   // drain everything (incl. dummy DMAs into scratch)

  // ---- epilogue: fused softmax over 1024 columns ----
  // col(cc) = (cc>>2)*512 + wid*64 + (cc&3)*16 + l15 ; row = rb*16 + g*4 + j
  float bcol[8];
  #pragma unroll
  for (int cc = 0; cc < 8; ++cc)
    bcol[cc] = bias_lds[(cc >> 2) * 512 + wid * 64 + (cc & 3) * 16 + l15];

  float rmax[4][4];
  #pragma unroll
  for (int rb = 0; rb < 4; ++rb) {
    #pragma unroll
    for (int j = 0; j < 4; ++j) {
      float m = -3.0e38f;
      #pragma unroll
      for (int cc = 0; cc < 8; ++cc) {
        float v = acc[rb][cc][j] + bcol[cc];
        acc[rb][cc][j] = v;
        m = fmaxf(m, v);
      }
      m = fmaxf(m, __shfl_xor(m, 1, 64));
      m = fmaxf(m, __shfl_xor(m, 2, 64));
      m = fmaxf(m, __shfl_xor(m, 4, 64));
      m = fmaxf(m, __shfl_xor(m, 8, 64));
      rmax[rb][j] = m;
    }
  }
  if (l15 == 0) {
    #pragma unroll
    for (int rb = 0; rb < 4; ++rb)
      #pragma unroll
      for (int j = 0; j < 4; ++j)
        red[wid * BM + rb * 16 + g * 4 + j] = rmax[rb][j];
  }
  __syncthreads();
  if (tid < BM) {
    float m = red[tid];
    #pragma unroll
    for (int w = 1; w < WAVES; ++w) m = fmaxf(m, red[w * BM + tid]);
    fin[tid] = m;
  }
  __syncthreads();

  #pragma unroll
  for (int rb = 0; rb < 4; ++rb) {
    #pragma unroll
    for (int j = 0; j < 4; ++j) {
      float m = fin[rb * 16 + g * 4 + j];
      float s = 0.f;
      #pragma unroll
      for (int cc = 0; cc < 8; ++cc) {
        float e = __expf(acc[rb][cc][j] - m);
        acc[rb][cc][j] = e;
        s += e;
      }
      s += __shfl_xor(s, 1, 64);
      s += __shfl_xor(s, 2, 64);
      s += __shfl_xor(s, 4, 64);
      s += __shfl_xor(s, 8, 64);
      rmax[rb][j] = s;
    }
  }
  __syncthreads();
  if (l15 == 0) {
    #pragma unroll
    for (int rb = 0; rb < 4; ++rb)
      #pragma unroll
      for (int j = 0; j < 4; ++j)
        red[wid * BM + rb * 16 + g * 4 + j] = rmax[rb][j];
  }
  __syncthreads();
  if (tid < BM) {
    float s = 0.f;
    #pragma unroll
    for (int w = 0; w < WAVES; ++w) s += red[w * BM + tid];
    fin[tid] = 1.0f / s;
  }
  __syncthreads();

  #pragma unroll
  for (int rb = 0; rb < 4; ++rb) {
    #pragma unroll
    for (int j = 0; j < 4; ++j) {
      const int row = rb * 16 + g * 4 + j;
      const float rs = fin[row];
      #pragma unroll
      for (int cc = 0; cc < 8; ++cc) {
        const int col = (cc >> 2) * 512 + wid * 64 + (cc & 3) * 16 + l15;
        out[(size_t)(brow + row) * K_CL + col] = acc[rb][cc][j] * rs;
      }
    }
  }
}

extern "C" void kernel_launch(void* const* d_in, const int* in_sizes, int n_in,
                              void* d_out, int out_size, void* d_ws, size_t ws_size,
                              hipStream_t stream) {
  const float* x       = (const float*)d_in[0];   // [32768, 512] fp32
  const float* centers = (const float*)d_in[1];   // [1024, 512] fp32
  float* out = (float*)d_out;                     // [32768, 1024] fp32

  bf16_t* bpack = (bf16_t*)d_ws;                                   // 64*32768B = 2MB
  float*  bias  = (float*)((char*)d_ws + (size_t)NSUB * 32768);    // 4KB

  prep_kernel<<<K_CL, 64, 0, stream>>>(centers, bpack, bias);
  cluster_kernel<<<N_ROWS / BM, THREADS, 0, stream>>>(x, bpack, bias, out);
}